// Round 2
// baseline (839.216 us; speedup 1.0000x reference)
//
#include <hip/hip_runtime.h>
#include <hip/hip_bf16.h>

#define M_CH 2
#define J_F 2000
#define I_F 2049
#define K_B 8
#define N_IT 5
#define NMF_EPS 1e-20f
#define IP_EPS 1e-20f
#define ICH 32     // i-chunks for V-update partials
#define CHSZ 65    // ceil(2049/32)
#define JCH 125    // j-chunks for D partials (125*16 = 2000)
#define JCHSZ 16

// ---------------- init: T[n][i][k], V[n][k][j], W[i] = eye ----------------
__global__ void k_init(const float* __restrict__ T0, const float* __restrict__ V0,
                       float* __restrict__ T, float* __restrict__ V, float* __restrict__ W) {
  int t = blockIdx.x * blockDim.x + threadIdx.x;
  int stride = gridDim.x * blockDim.x;
  for (int idx = t; idx < 2 * I_F * K_B; idx += stride) {
    int n = idx / (I_F * K_B);
    int r = idx % (I_F * K_B);
    int i = r / K_B, k = r % K_B;
    T[idx] = T0[(i * K_B + k) * M_CH + n];
  }
  for (int idx = t; idx < 2 * K_B * J_F; idx += stride) {
    int n = idx / (K_B * J_F);
    int r = idx % (K_B * J_F);
    int k = r / J_F, j = r % J_F;
    V[idx] = V0[(k * J_F + j) * M_CH + n];
  }
  for (int i = t; i < I_F; i += stride) {
    W[i * 8 + 0] = 1.f; W[i * 8 + 1] = 0.f; W[i * 8 + 2] = 0.f; W[i * 8 + 3] = 0.f;
    W[i * 8 + 4] = 0.f; W[i * 8 + 5] = 0.f; W[i * 8 + 6] = 1.f; W[i * 8 + 7] = 0.f;
  }
}

// ---------------- P[n][i][j] = |Y[i,n,j]|^2, LDS-tiled transpose ----------------
__global__ __launch_bounds__(256) void k_computeP(const float2* __restrict__ X,
                                                  const float* __restrict__ W,
                                                  float* __restrict__ P) {
  __shared__ float Wl[64][8];
  __shared__ float Pl0[64][65];
  __shared__ float Pl1[64][65];
  const int tid = threadIdx.x;
  const int i0 = blockIdx.x * 64;
  const int j0 = blockIdx.y * 64;
  if (tid < 64) {
    int i = i0 + tid;
    if (i < I_F) {
#pragma unroll
      for (int c = 0; c < 8; ++c) Wl[tid][c] = W[i * 8 + c];
    }
  }
  __syncthreads();
  const int il = tid & 63;
#pragma unroll 4
  for (int s = 0; s < 16; ++s) {
    int jl = (tid >> 6) + s * 4;
    int i = i0 + il, j = j0 + jl;
    if (i < I_F && j < J_F) {
      float2 x0 = X[(size_t)j * I_F + i];
      float2 x1 = X[(size_t)(J_F + j) * I_F + i];
      float w0r = Wl[il][0], w0i = Wl[il][1], w1r = Wl[il][2], w1i = Wl[il][3];
      float yr = w0r * x0.x - w0i * x0.y + w1r * x1.x - w1i * x1.y;
      float yi = w0r * x0.y + w0i * x0.x + w1r * x1.y + w1i * x1.x;
      Pl0[il][jl] = yr * yr + yi * yi;
      float u0r = Wl[il][4], u0i = Wl[il][5], u1r = Wl[il][6], u1i = Wl[il][7];
      float zr = u0r * x0.x - u0i * x0.y + u1r * x1.x - u1i * x1.y;
      float zi = u0r * x0.y + u0i * x0.x + u1r * x1.y + u1i * x1.x;
      Pl1[il][jl] = zr * zr + zi * zi;
    }
  }
  __syncthreads();
  const int jl = tid & 63;
#pragma unroll 4
  for (int s = 0; s < 16; ++s) {
    int ilw = (tid >> 6) + s * 4;
    int i = i0 + ilw, j = j0 + jl;
    if (i < I_F && j < J_F) {
      P[(size_t)i * J_F + j] = Pl0[ilw][jl];
      P[(size_t)(I_F + i) * J_F + j] = Pl1[ilw][jl];
    }
  }
}

// ---------------- NMF T-update: one block per row i ----------------
__global__ __launch_bounds__(256) void k_t_update(const float* __restrict__ P,
                                                  float* __restrict__ T,
                                                  const float* __restrict__ V) {
  const int i = blockIdx.x;
  const int tid = threadIdx.x;
  float Trow[K_B];
#pragma unroll
  for (int k = 0; k < K_B; ++k) Trow[k] = T[i * K_B + k];
  float num[K_B], den[K_B];
#pragma unroll
  for (int k = 0; k < K_B; ++k) { num[k] = 0.f; den[k] = 0.f; }
  for (int j = tid; j < J_F; j += 256) {
    float p = P[(size_t)i * J_F + j];
    float vk[K_B];
    float R = 0.f;
#pragma unroll
    for (int k = 0; k < K_B; ++k) { vk[k] = V[k * J_F + j]; R += Trow[k] * vk[k]; }
    float w1 = p / (R * R);
    float w2 = 1.0f / R;
#pragma unroll
    for (int k = 0; k < K_B; ++k) { num[k] += w1 * vk[k]; den[k] += w2 * vk[k]; }
  }
  __shared__ float red[4][16];
  const int lane = tid & 63, wid = tid >> 6;
#pragma unroll
  for (int k = 0; k < K_B; ++k) {
    float a = num[k], b = den[k];
#pragma unroll
    for (int off = 32; off > 0; off >>= 1) {
      a += __shfl_xor(a, off, 64);
      b += __shfl_xor(b, off, 64);
    }
    if (lane == 0) { red[wid][k] = a; red[wid][8 + k] = b; }
  }
  __syncthreads();
  if (tid < 16) red[0][tid] = red[0][tid] + red[1][tid] + red[2][tid] + red[3][tid];
  __syncthreads();
  if (tid < 8) {
    float t = T[i * K_B + tid];
    float r = sqrtf(red[0][tid] / red[0][8 + tid]);
    T[i * K_B + tid] = fmaxf(t * r, NMF_EPS);
  }
}

// ---------------- NMF V-update partials over i-chunks ----------------
__global__ __launch_bounds__(256) void k_v_partial(const float* __restrict__ P,
                                                   const float* __restrict__ T,
                                                   const float* __restrict__ V,
                                                   float* __restrict__ Vpart) {
  const int j = blockIdx.x * 256 + threadIdx.x;
  if (j >= J_F) return;
  const int ic = blockIdx.y;
  const int i0 = ic * CHSZ;
  const int i1 = min(I_F, i0 + CHSZ);
  float vold[K_B];
#pragma unroll
  for (int k = 0; k < K_B; ++k) vold[k] = V[k * J_F + j];
  float num[K_B], den[K_B];
#pragma unroll
  for (int k = 0; k < K_B; ++k) { num[k] = 0.f; den[k] = 0.f; }
  for (int i = i0; i < i1; ++i) {
    float p = P[(size_t)i * J_F + j];
    float R = 0.f;
    float tk[K_B];
#pragma unroll
    for (int k = 0; k < K_B; ++k) { tk[k] = T[i * K_B + k]; R += tk[k] * vold[k]; }
    float w1 = p / (R * R);
    float w2 = 1.0f / R;
#pragma unroll
    for (int k = 0; k < K_B; ++k) { num[k] += tk[k] * w1; den[k] += tk[k] * w2; }
  }
#pragma unroll
  for (int k = 0; k < K_B; ++k) {
    ((float2*)Vpart)[(size_t)(ic * K_B + k) * J_F + j] = make_float2(num[k], den[k]);
  }
}

__global__ void k_v_combine(const float* __restrict__ Vpart, float* __restrict__ V) {
  int t = blockIdx.x * blockDim.x + threadIdx.x;
  if (t >= K_B * J_F) return;
  int k = t / J_F, j = t % J_F;
  float num = 0.f, den = 0.f;
  for (int ic = 0; ic < ICH; ++ic) {
    float2 nd = ((const float2*)Vpart)[(size_t)(ic * K_B + k) * J_F + j];
    num += nd.x; den += nd.y;
  }
  float v = V[t];
  V[t] = fmaxf(v * sqrtf(num / den), NMF_EPS);
}

// ---------------- weighted covariance D partials over j-chunks ----------------
__global__ __launch_bounds__(64) void k_d_partial(const float2* __restrict__ X,
                                                  const float* __restrict__ T,
                                                  const float* __restrict__ V,
                                                  float* __restrict__ Dpart) {
  const int i = blockIdx.x * 64 + threadIdx.x;
  if (i >= I_F) return;
  const int j0 = blockIdx.y * JCHSZ;
  float Trow[K_B];
#pragma unroll
  for (int k = 0; k < K_B; ++k) Trow[k] = T[i * K_B + k];
  float d00 = 0.f, d11 = 0.f, d01r = 0.f, d01i = 0.f;
  for (int jj = 0; jj < JCHSZ; ++jj) {
    int j = j0 + jj;
    float R = 0.f;
#pragma unroll
    for (int k = 0; k < K_B; ++k) R += Trow[k] * V[k * J_F + j];
    float w = 1.0f / (R + IP_EPS);
    float2 x0 = X[(size_t)j * I_F + i];
    float2 x1 = X[(size_t)(J_F + j) * I_F + i];
    d00 += w * (x0.x * x0.x + x0.y * x0.y);
    d11 += w * (x1.x * x1.x + x1.y * x1.y);
    d01r += w * (x0.x * x1.x + x0.y * x1.y);
    d01i += w * (x0.y * x1.x - x0.x * x1.y);
  }
  ((float4*)Dpart)[(size_t)blockIdx.y * I_F + i] = make_float4(d00, d11, d01r, d01i);
}

// ---------------- combine D, 2x2 complex solve, update W row n ----------------
__global__ __launch_bounds__(64) void k_d_combine(const float* __restrict__ Dpart,
                                                  float* __restrict__ W, int n) {
  const int i = blockIdx.x * 64 + threadIdx.x;
  if (i >= I_F) return;
  float d00 = 0.f, d11 = 0.f, d01r = 0.f, d01i = 0.f;
  for (int c = 0; c < JCH; ++c) {
    float4 d = ((const float4*)Dpart)[(size_t)c * I_F + i];
    d00 += d.x; d11 += d.y; d01r += d.z; d01i += d.w;
  }
  const float invJ = 1.0f / (float)J_F;
  d00 = d00 * invJ + IP_EPS;
  d11 = d11 * invJ + IP_EPS;
  d01r *= invJ; d01i *= invJ;
  float w00r = W[i*8+0], w00i = W[i*8+1], w01r = W[i*8+2], w01i = W[i*8+3];
  float w10r = W[i*8+4], w10i = W[i*8+5], w11r = W[i*8+6], w11i = W[i*8+7];
  // A = W @ Dreg;  D00=(d00,0) D01=(d01r,d01i) D10=conj(D01) D11=(d11,0)
  float A00r = w00r * d00 + (w01r * d01r + w01i * d01i);
  float A00i = w00i * d00 + (w01i * d01r - w01r * d01i);
  float A01r = (w00r * d01r - w00i * d01i) + w01r * d11;
  float A01i = (w00r * d01i + w00i * d01r) + w01i * d11;
  float A10r = w10r * d00 + (w11r * d01r + w11i * d01i);
  float A10i = w10i * d00 + (w11i * d01r - w11r * d01i);
  float A11r = (w10r * d01r - w10i * d01i) + w11r * d11;
  float A11i = (w10r * d01i + w10i * d01r) + w11i * d11;
  float detr = (A00r * A11r - A00i * A11i) - (A01r * A10r - A01i * A10i);
  float deti = (A00r * A11i + A00i * A11r) - (A01r * A10i + A01i * A10r);
  float idet = 1.0f / (detr * detr + deti * deti);
  float n0r, n0i, n1r, n1i;
  if (n == 0) { n0r = A11r; n0i = A11i; n1r = -A10r; n1i = -A10i; }
  else        { n0r = -A01r; n0i = -A01i; n1r = A00r; n1i = A00i; }
  float b0r = (n0r * detr + n0i * deti) * idet;
  float b0i = (n0i * detr - n0r * deti) * idet;
  float b1r = (n1r * detr + n1i * deti) * idet;
  float b1i = (n1i * detr - n1r * deti) * idet;
  // quad = b^H Dreg b (real)
  float cr = d01r * b1r - d01i * b1i;
  float ci = d01r * b1i + d01i * b1r;
  float quad = d00 * (b0r * b0r + b0i * b0i) + d11 * (b1r * b1r + b1i * b1i)
             + 2.0f * (b0r * cr + b0i * ci);
  float s = 1.0f / sqrtf(quad + IP_EPS);
  W[i * 8 + n * 4 + 0] = b0r * s;
  W[i * 8 + n * 4 + 1] = -b0i * s;
  W[i * 8 + n * 4 + 2] = b1r * s;
  W[i * 8 + n * 4 + 3] = -b1i * s;
}

// ---------------- final: out[n][j][i][2] = Y[i,n,j] ----------------
__global__ __launch_bounds__(256) void k_final(const float2* __restrict__ X,
                                               const float* __restrict__ W,
                                               float2* __restrict__ out) {
  const int i = blockIdx.x * 256 + threadIdx.x;
  if (i >= I_F) return;
  const int j = blockIdx.y;
  float2 x0 = X[(size_t)j * I_F + i];
  float2 x1 = X[(size_t)(J_F + j) * I_F + i];
  float4 wa = ((const float4*)W)[i * 2];
  float4 wb = ((const float4*)W)[i * 2 + 1];
  float y0r = wa.x * x0.x - wa.y * x0.y + wa.z * x1.x - wa.w * x1.y;
  float y0i = wa.x * x0.y + wa.y * x0.x + wa.z * x1.y + wa.w * x1.x;
  out[(size_t)j * I_F + i] = make_float2(y0r, y0i);
  float y1r = wb.x * x0.x - wb.y * x0.y + wb.z * x1.x - wb.w * x1.y;
  float y1i = wb.x * x0.y + wb.y * x0.x + wb.z * x1.y + wb.w * x1.x;
  out[(size_t)(J_F + j) * I_F + i] = make_float2(y1r, y1i);
}

extern "C" void kernel_launch(void* const* d_in, const int* in_sizes, int n_in,
                              void* d_out, int out_size, void* d_ws, size_t ws_size,
                              hipStream_t stream) {
  const float2* X = (const float2*)d_in[0];
  const float* T0 = (const float*)d_in[1];
  const float* V0 = (const float*)d_in[2];
  char* ws = (char*)d_ws;
  size_t off = 0;
  auto alloc = [&](size_t bytes) -> void* {
    void* p = ws + off;
    off = (off + bytes + 255) & ~(size_t)255;
    return p;
  };
  float* W = (float*)alloc((size_t)I_F * 8 * 4);
  float* T = (float*)alloc((size_t)2 * I_F * K_B * 4);
  float* V = (float*)alloc((size_t)2 * K_B * J_F * 4);
  float* P = (float*)alloc((size_t)2 * I_F * J_F * 4);
  float* Vpart = (float*)alloc((size_t)ICH * K_B * J_F * 2 * 4);
  float* Dpart = (float*)alloc((size_t)JCH * I_F * 4 * 4);

  k_init<<<128, 256, 0, stream>>>(T0, V0, T, V, W);
  for (int it = 0; it < N_IT; ++it) {
    k_computeP<<<dim3(33, 32), 256, 0, stream>>>(X, W, P);
    for (int n = 0; n < 2; ++n) {
      float* Pn = P + (size_t)n * I_F * J_F;
      float* Tn = T + (size_t)n * I_F * K_B;
      float* Vn = V + (size_t)n * K_B * J_F;
      k_t_update<<<I_F, 256, 0, stream>>>(Pn, Tn, Vn);
      k_v_partial<<<dim3(8, ICH), 256, 0, stream>>>(Pn, Tn, Vn, Vpart);
      k_v_combine<<<(K_B * J_F + 255) / 256, 256, 0, stream>>>(Vpart, Vn);
      k_d_partial<<<dim3(33, JCH), 64, 0, stream>>>(X, Tn, Vn, Dpart);
      k_d_combine<<<33, 64, 0, stream>>>(Dpart, W, n);
    }
  }
  k_final<<<dim3(9, J_F), 256, 0, stream>>>(X, W, (float2*)d_out);
}

// Round 3
// 693.811 us; speedup vs baseline: 1.2096x; 1.2096x over previous
//
#include <hip/hip_runtime.h>
#include <hip/hip_bf16.h>

#define M_CH 2
#define J_F 2000
#define I_F 2049
#define K_B 8
#define N_IT 5
#define NMF_EPS 1e-20f
#define IP_EPS 1e-20f
#define ICH 16      // i-chunks for V-update partials
#define CHSZ 129    // ceil(2049/16)
#define JCH 50      // j-chunks for D partials
#define JCHSZ 40    // 50*40 = 2000 exactly
#define JTILES 32   // j-tiles in P kernel (32*64 >= 2000)

// ---------------- init: T[n][i][k], V[n][k][j], W[i] = eye ----------------
__global__ void k_init(const float* __restrict__ T0, const float* __restrict__ V0,
                       float* __restrict__ T, float* __restrict__ V, float* __restrict__ W) {
  int t = blockIdx.x * blockDim.x + threadIdx.x;
  int stride = gridDim.x * blockDim.x;
  for (int idx = t; idx < 2 * I_F * K_B; idx += stride) {
    int n = idx / (I_F * K_B);
    int r = idx % (I_F * K_B);
    int i = r / K_B, k = r % K_B;
    T[idx] = T0[(i * K_B + k) * M_CH + n];
  }
  for (int idx = t; idx < 2 * K_B * J_F; idx += stride) {
    int n = idx / (K_B * J_F);
    int r = idx % (K_B * J_F);
    int k = r / J_F, j = r % J_F;
    V[idx] = V0[(k * J_F + j) * M_CH + n];
  }
  for (int i = t; i < I_F; i += stride) {
    W[i * 8 + 0] = 1.f; W[i * 8 + 1] = 0.f; W[i * 8 + 2] = 0.f; W[i * 8 + 3] = 0.f;
    W[i * 8 + 4] = 0.f; W[i * 8 + 5] = 0.f; W[i * 8 + 6] = 1.f; W[i * 8 + 7] = 0.f;
  }
}

// ---- P[n][i][j] = |Y[i,n,j]|^2 (LDS transpose) + fused T-update partials ----
__global__ __launch_bounds__(256) void k_P_T(const float2* __restrict__ X,
                                             const float* __restrict__ W,
                                             const float* __restrict__ T,
                                             const float* __restrict__ V,
                                             float* __restrict__ P,
                                             float* __restrict__ Tpart) {
  __shared__ float Wl[64][8];
  __shared__ float Tl[2][64][8];
  __shared__ float Vl[2][8][64];
  __shared__ float Pl[2][64][65];
  __shared__ float Red[4][16][64];
  const int tid = threadIdx.x;
  const int i0 = blockIdx.x * 64, j0 = blockIdx.y * 64;
  for (int idx = tid; idx < 512; idx += 256) {
    int r = idx >> 3, c = idx & 7;
    int i = i0 + r;
    float w = 0.f, ta = 0.f, tb = 0.f;
    if (i < I_F) { w = W[i * 8 + c]; ta = T[i * 8 + c]; tb = T[I_F * 8 + i * 8 + c]; }
    Wl[r][c] = w; Tl[0][r][c] = ta; Tl[1][r][c] = tb;
  }
  for (int idx = tid; idx < 1024; idx += 256) {
    int n = idx >> 9, r = (idx >> 6) & 7, c = idx & 63;
    int j = j0 + c;
    Vl[n][r][c] = (j < J_F) ? V[n * K_B * J_F + r * J_F + j] : 1.f;
  }
  __syncthreads();
  const int il = tid & 63, grp = tid >> 6;
  const int gi = i0 + il;
  const bool irow = gi < I_F;
  float t0[K_B], t1[K_B];
#pragma unroll
  for (int k = 0; k < K_B; ++k) { t0[k] = Tl[0][il][k]; t1[k] = Tl[1][il][k]; }
  const float w0r = Wl[il][0], w0i = Wl[il][1], w1r = Wl[il][2], w1i = Wl[il][3];
  const float u0r = Wl[il][4], u0i = Wl[il][5], u1r = Wl[il][6], u1i = Wl[il][7];
  float num0[K_B] = {}, den0[K_B] = {}, num1[K_B] = {}, den1[K_B] = {};
#pragma unroll 4
  for (int s = 0; s < 16; ++s) {
    const int jl = grp + s * 4;
    const int j = j0 + jl;
    const bool ok = irow && (j < J_F);
    float2 x0 = make_float2(0.f, 0.f), x1 = make_float2(0.f, 0.f);
    if (ok) { x0 = X[(size_t)j * I_F + gi]; x1 = X[(size_t)(J_F + j) * I_F + gi]; }
    float yr = w0r * x0.x - w0i * x0.y + w1r * x1.x - w1i * x1.y;
    float yi = w0r * x0.y + w0i * x0.x + w1r * x1.y + w1i * x1.x;
    float p0 = yr * yr + yi * yi;
    float zr = u0r * x0.x - u0i * x0.y + u1r * x1.x - u1i * x1.y;
    float zi = u0r * x0.y + u0i * x0.x + u1r * x1.y + u1i * x1.x;
    float p1 = zr * zr + zi * zi;
    Pl[0][il][jl] = p0; Pl[1][il][jl] = p1;
    if (ok) {
      float v0[K_B], v1[K_B];
      float R0 = 0.f, R1 = 0.f;
#pragma unroll
      for (int k = 0; k < K_B; ++k) {
        v0[k] = Vl[0][k][jl]; R0 += t0[k] * v0[k];
        v1[k] = Vl[1][k][jl]; R1 += t1[k] * v1[k];
      }
      float a0 = p0 / (R0 * R0), b0 = 1.f / R0;
      float a1 = p1 / (R1 * R1), b1 = 1.f / R1;
#pragma unroll
      for (int k = 0; k < K_B; ++k) {
        num0[k] += a0 * v0[k]; den0[k] += b0 * v0[k];
        num1[k] += a1 * v1[k]; den1[k] += b1 * v1[k];
      }
    }
  }
  __syncthreads();
  // transposed P write (coalesced along j)
  {
    const int jl2 = tid & 63;
    const int gj = j0 + jl2;
#pragma unroll 4
    for (int s = 0; s < 16; ++s) {
      int r = grp + s * 4, i = i0 + r;
      if (i < I_F && gj < J_F) {
        P[(size_t)i * J_F + gj] = Pl[0][r][jl2];
        P[(size_t)(I_F + i) * J_F + gj] = Pl[1][r][jl2];
      }
    }
  }
  // T partials, n = 0
#pragma unroll
  for (int k = 0; k < K_B; ++k) { Red[grp][k][il] = num0[k]; Red[grp][8 + k][il] = den0[k]; }
  __syncthreads();
  {
    int r = tid & 63, q0 = (tid >> 6) * 4;
    int i = i0 + r;
    float4 o;
    float* po = (float*)&o;
#pragma unroll
    for (int qi = 0; qi < 4; ++qi) {
      int q = q0 + qi;
      po[qi] = Red[0][q][r] + Red[1][q][r] + Red[2][q][r] + Red[3][q][r];
    }
    if (i < I_F)
      *(float4*)&Tpart[(((size_t)0 * JTILES + blockIdx.y) * I_F + i) * 16 + q0] = o;
  }
  __syncthreads();
  // T partials, n = 1
#pragma unroll
  for (int k = 0; k < K_B; ++k) { Red[grp][k][il] = num1[k]; Red[grp][8 + k][il] = den1[k]; }
  __syncthreads();
  {
    int r = tid & 63, q0 = (tid >> 6) * 4;
    int i = i0 + r;
    float4 o;
    float* po = (float*)&o;
#pragma unroll
    for (int qi = 0; qi < 4; ++qi) {
      int q = q0 + qi;
      po[qi] = Red[0][q][r] + Red[1][q][r] + Red[2][q][r] + Red[3][q][r];
    }
    if (i < I_F)
      *(float4*)&Tpart[(((size_t)JTILES + blockIdx.y) * I_F + i) * 16 + q0] = o;
  }
}

// ---------------- finish T update from partials ----------------
__global__ __launch_bounds__(256) void k_t_finish(const float* __restrict__ Tpart,
                                                  float* __restrict__ T) {
  int t = blockIdx.x * 256 + threadIdx.x;
  if (t >= 2 * I_F * K_B) return;
  int n = t / (I_F * K_B);
  int r = t % (I_F * K_B);
  int i = r >> 3, k = r & 7;
  float num = 0.f, den = 0.f;
  for (int jt = 0; jt < JTILES; ++jt) {
    const float* p = Tpart + (((size_t)n * JTILES + jt) * I_F + i) * 16;
    num += p[k]; den += p[8 + k];
  }
  float told = T[t];
  T[t] = fmaxf(told * sqrtf(num / den), NMF_EPS);
}

// ---------------- NMF V-update partials over i-chunks (both n via z) ----------------
__global__ __launch_bounds__(256) void k_v_partial(const float* __restrict__ P,
                                                   const float* __restrict__ T,
                                                   const float* __restrict__ V,
                                                   float* __restrict__ Vpart) {
  const int n = blockIdx.z;
  const int j = blockIdx.x * 256 + threadIdx.x;
  if (j >= J_F) return;
  const int ic = blockIdx.y;
  const int i0c = ic * CHSZ;
  const int i1c = min(I_F, i0c + CHSZ);
  const float* Pn = P + (size_t)n * I_F * J_F;
  const float* Tn = T + (size_t)n * I_F * K_B;
  const float* Vn = V + (size_t)n * K_B * J_F;
  float vold[K_B];
#pragma unroll
  for (int k = 0; k < K_B; ++k) vold[k] = Vn[k * J_F + j];
  float num[K_B] = {}, den[K_B] = {};
  for (int i = i0c; i < i1c; ++i) {
    float p = Pn[(size_t)i * J_F + j];
    float tk[K_B];
    float R = 0.f;
#pragma unroll
    for (int k = 0; k < K_B; ++k) { tk[k] = Tn[i * K_B + k]; R += tk[k] * vold[k]; }
    float a = p / (R * R);
    float b = 1.0f / R;
#pragma unroll
    for (int k = 0; k < K_B; ++k) { num[k] += a * tk[k]; den[k] += b * tk[k]; }
  }
  float2* vp = (float2*)Vpart;
#pragma unroll
  for (int k = 0; k < K_B; ++k)
    vp[(((size_t)n * ICH + ic) * K_B + k) * J_F + j] = make_float2(num[k], den[k]);
}

__global__ __launch_bounds__(256) void k_v_combine(const float* __restrict__ Vpart,
                                                   float* __restrict__ V) {
  int t = blockIdx.x * 256 + threadIdx.x;
  if (t >= 2 * K_B * J_F) return;
  int n = t / (K_B * J_F);
  int r = t % (K_B * J_F);
  int k = r / J_F, j = r % J_F;
  const float2* vp = (const float2*)Vpart;
  float num = 0.f, den = 0.f;
  for (int ic = 0; ic < ICH; ++ic) {
    float2 nd = vp[(((size_t)n * ICH + ic) * K_B + k) * J_F + j];
    num += nd.x; den += nd.y;
  }
  float v = V[t];
  V[t] = fmaxf(v * sqrtf(num / den), NMF_EPS);
}

// -------- weighted covariance partials, both n share X loads --------
__global__ __launch_bounds__(256) void k_d_partial(const float2* __restrict__ X,
                                                   const float* __restrict__ T,
                                                   const float* __restrict__ V,
                                                   float* __restrict__ Dpart) {
  const int i = blockIdx.x * 256 + threadIdx.x;
  if (i >= I_F) return;
  const int j0 = blockIdx.y * JCHSZ;
  float t0[K_B], t1[K_B];
#pragma unroll
  for (int k = 0; k < K_B; ++k) { t0[k] = T[i * K_B + k]; t1[k] = T[I_F * K_B + i * K_B + k]; }
  float a00 = 0.f, a11 = 0.f, a01r = 0.f, a01i = 0.f;
  float b00 = 0.f, b11 = 0.f, b01r = 0.f, b01i = 0.f;
  for (int jj = 0; jj < JCHSZ; ++jj) {
    int j = j0 + jj;
    float R0 = 0.f, R1 = 0.f;
#pragma unroll
    for (int k = 0; k < K_B; ++k) {
      R0 += t0[k] * V[k * J_F + j];
      R1 += t1[k] * V[K_B * J_F + k * J_F + j];
    }
    float wv0 = 1.0f / (R0 + IP_EPS);
    float wv1 = 1.0f / (R1 + IP_EPS);
    float2 x0 = X[(size_t)j * I_F + i];
    float2 x1 = X[(size_t)(J_F + j) * I_F + i];
    float p00 = x0.x * x0.x + x0.y * x0.y;
    float p11 = x1.x * x1.x + x1.y * x1.y;
    float pr = x0.x * x1.x + x0.y * x1.y;
    float pi = x0.y * x1.x - x0.x * x1.y;
    a00 += wv0 * p00; a11 += wv0 * p11; a01r += wv0 * pr; a01i += wv0 * pi;
    b00 += wv1 * p00; b11 += wv1 * p11; b01r += wv1 * pr; b01i += wv1 * pi;
  }
  float4* dp = (float4*)Dpart;
  dp[((size_t)0 * JCH + blockIdx.y) * I_F + i] = make_float4(a00, a11, a01r, a01i);
  dp[((size_t)1 * JCH + blockIdx.y) * I_F + i] = make_float4(b00, b11, b01r, b01i);
}

// -------- combine D + sequential 2x2 complex solves (n=0 then n=1) --------
__global__ __launch_bounds__(256) void k_d_solve(const float* __restrict__ Dpart,
                                                 float* __restrict__ W) {
  const int i = blockIdx.x * 256 + threadIdx.x;
  if (i >= I_F) return;
  float4 wa = ((const float4*)W)[i * 2];
  float4 wb = ((const float4*)W)[i * 2 + 1];
  float w00r = wa.x, w00i = wa.y, w01r = wa.z, w01i = wa.w;
  float w10r = wb.x, w10i = wb.y, w11r = wb.z, w11i = wb.w;
  const float invJ = 1.0f / (float)J_F;
#pragma unroll
  for (int n = 0; n < 2; ++n) {
    float d00 = 0.f, d11 = 0.f, d01r = 0.f, d01i = 0.f;
    for (int c = 0; c < JCH; ++c) {
      float4 d = ((const float4*)Dpart)[((size_t)n * JCH + c) * I_F + i];
      d00 += d.x; d11 += d.y; d01r += d.z; d01i += d.w;
    }
    d00 = d00 * invJ + IP_EPS;
    d11 = d11 * invJ + IP_EPS;
    d01r *= invJ; d01i *= invJ;
    float A00r = w00r * d00 + (w01r * d01r + w01i * d01i);
    float A00i = w00i * d00 + (w01i * d01r - w01r * d01i);
    float A01r = (w00r * d01r - w00i * d01i) + w01r * d11;
    float A01i = (w00r * d01i + w00i * d01r) + w01i * d11;
    float A10r = w10r * d00 + (w11r * d01r + w11i * d01i);
    float A10i = w10i * d00 + (w11i * d01r - w11r * d01i);
    float A11r = (w10r * d01r - w10i * d01i) + w11r * d11;
    float A11i = (w10r * d01i + w10i * d01r) + w11i * d11;
    float detr = (A00r * A11r - A00i * A11i) - (A01r * A10r - A01i * A10i);
    float deti = (A00r * A11i + A00i * A11r) - (A01r * A10i + A01i * A10r);
    float idet = 1.0f / (detr * detr + deti * deti);
    float n0r, n0i, n1r, n1i;
    if (n == 0) { n0r = A11r; n0i = A11i; n1r = -A10r; n1i = -A10i; }
    else        { n0r = -A01r; n0i = -A01i; n1r = A00r; n1i = A00i; }
    float b0r = (n0r * detr + n0i * deti) * idet;
    float b0i = (n0i * detr - n0r * deti) * idet;
    float b1r = (n1r * detr + n1i * deti) * idet;
    float b1i = (n1i * detr - n1r * deti) * idet;
    float cr = d01r * b1r - d01i * b1i;
    float ci = d01r * b1i + d01i * b1r;
    float quad = d00 * (b0r * b0r + b0i * b0i) + d11 * (b1r * b1r + b1i * b1i)
               + 2.0f * (b0r * cr + b0i * ci);
    float s = 1.0f / sqrtf(quad + IP_EPS);
    if (n == 0) { w00r = b0r * s; w00i = -b0i * s; w01r = b1r * s; w01i = -b1i * s; }
    else        { w10r = b0r * s; w10i = -b0i * s; w11r = b1r * s; w11i = -b1i * s; }
  }
  ((float4*)W)[i * 2]     = make_float4(w00r, w00i, w01r, w01i);
  ((float4*)W)[i * 2 + 1] = make_float4(w10r, w10i, w11r, w11i);
}

// ---------------- final: out[n][j][i][2] = Y[i,n,j] ----------------
__global__ __launch_bounds__(256) void k_final(const float2* __restrict__ X,
                                               const float* __restrict__ W,
                                               float2* __restrict__ out) {
  const int i = blockIdx.x * 256 + threadIdx.x;
  if (i >= I_F) return;
  const int j = blockIdx.y;
  float2 x0 = X[(size_t)j * I_F + i];
  float2 x1 = X[(size_t)(J_F + j) * I_F + i];
  float4 wa = ((const float4*)W)[i * 2];
  float4 wb = ((const float4*)W)[i * 2 + 1];
  float y0r = wa.x * x0.x - wa.y * x0.y + wa.z * x1.x - wa.w * x1.y;
  float y0i = wa.x * x0.y + wa.y * x0.x + wa.z * x1.y + wa.w * x1.x;
  out[(size_t)j * I_F + i] = make_float2(y0r, y0i);
  float y1r = wb.x * x0.x - wb.y * x0.y + wb.z * x1.x - wb.w * x1.y;
  float y1i = wb.x * x0.y + wb.y * x0.x + wb.z * x1.y + wb.w * x1.x;
  out[(size_t)(J_F + j) * I_F + i] = make_float2(y1r, y1i);
}

extern "C" void kernel_launch(void* const* d_in, const int* in_sizes, int n_in,
                              void* d_out, int out_size, void* d_ws, size_t ws_size,
                              hipStream_t stream) {
  const float2* X = (const float2*)d_in[0];
  const float* T0 = (const float*)d_in[1];
  const float* V0 = (const float*)d_in[2];
  char* ws = (char*)d_ws;
  size_t off = 0;
  auto alloc = [&](size_t bytes) -> void* {
    void* p = ws + off;
    off = (off + bytes + 255) & ~(size_t)255;
    return p;
  };
  float* W = (float*)alloc((size_t)I_F * 8 * 4);
  float* T = (float*)alloc((size_t)2 * I_F * K_B * 4);
  float* V = (float*)alloc((size_t)2 * K_B * J_F * 4);
  float* P = (float*)alloc((size_t)2 * I_F * J_F * 4);
  // Tpart (8.39 MB), Vpart (4.1 MB), Dpart (3.28 MB) have disjoint lifetimes -> share
  float* Scr = (float*)alloc((size_t)2 * JTILES * I_F * 16 * 4);
  float* Tpart = Scr;
  float* Vpart = Scr;
  float* Dpart = Scr;

  k_init<<<128, 256, 0, stream>>>(T0, V0, T, V, W);
  for (int it = 0; it < N_IT; ++it) {
    k_P_T<<<dim3(33, JTILES), 256, 0, stream>>>(X, W, T, V, P, Tpart);
    k_t_finish<<<129, 256, 0, stream>>>(Tpart, T);
    k_v_partial<<<dim3(8, ICH, 2), 256, 0, stream>>>(P, T, V, Vpart);
    k_v_combine<<<125, 256, 0, stream>>>(Vpart, V);
    k_d_partial<<<dim3(9, JCH), 256, 0, stream>>>(X, T, V, Dpart);
    k_d_solve<<<9, 256, 0, stream>>>(Dpart, W);
  }
  k_final<<<dim3(9, J_F), 256, 0, stream>>>(X, W, (float2*)d_out);
}

// Round 4
// 501.610 us; speedup vs baseline: 1.6730x; 1.3832x over previous
//
#include <hip/hip_runtime.h>
#include <hip/hip_bf16.h>

#define M_CH 2
#define J_F 2000
#define I_F 2049
#define K_B 8
#define N_IT 5
#define NMF_EPS 1e-20f
#define IP_EPS 1e-20f
#define JCH 50      // j-chunks for D partials
#define JCHSZ 40    // 50*40 = 2000 exactly
#define PJT 64      // j-tiles in P kernel
#define PJSZ 32     // 64*32 = 2048 >= 2000
#define IB 2304     // 9*256 padded i range

// ---------------- init: T[n][i][k], V[n][k][j], W[i] = eye ----------------
__global__ void k_init(const float* __restrict__ T0, const float* __restrict__ V0,
                       float* __restrict__ T, float* __restrict__ V, float* __restrict__ W) {
  int t = blockIdx.x * blockDim.x + threadIdx.x;
  int stride = gridDim.x * blockDim.x;
  for (int idx = t; idx < 2 * I_F * K_B; idx += stride) {
    int n = idx / (I_F * K_B);
    int r = idx % (I_F * K_B);
    int i = r / K_B, k = r % K_B;
    T[idx] = T0[(i * K_B + k) * M_CH + n];
  }
  for (int idx = t; idx < 2 * K_B * J_F; idx += stride) {
    int n = idx / (K_B * J_F);
    int r = idx % (K_B * J_F);
    int k = r / J_F, j = r % J_F;
    V[idx] = V0[(k * J_F + j) * M_CH + n];
  }
  for (int i = t; i < I_F; i += stride) {
    W[i * 8 + 0] = 1.f; W[i * 8 + 1] = 0.f; W[i * 8 + 2] = 0.f; W[i * 8 + 3] = 0.f;
    W[i * 8 + 4] = 0.f; W[i * 8 + 5] = 0.f; W[i * 8 + 6] = 1.f; W[i * 8 + 7] = 0.f;
  }
}

// ---- P[n][j][i] = |Y[i,n,j]|^2 (all coalesced) + lane-local T partials ----
__global__ __launch_bounds__(256) void k_P_T(const float2* __restrict__ X,
                                             const float* __restrict__ W,
                                             const float* __restrict__ T,
                                             const float* __restrict__ V,
                                             float* __restrict__ P,
                                             float* __restrict__ Tpart) {
  __shared__ float Vl[2][K_B][PJSZ];
  const int tid = threadIdx.x;
  const int j0 = blockIdx.y * PJSZ;
  for (int idx = tid; idx < 2 * K_B * PJSZ; idx += 256) {
    int n = idx >> 8, r = idx & 255;
    int k = r >> 5, jj = r & 31;
    int j = j0 + jj;
    Vl[n][k][jj] = (j < J_F) ? V[((size_t)n * K_B + k) * J_F + j] : 1.f;
  }
  __syncthreads();
  const int i = blockIdx.x * 256 + tid;
  if (i >= I_F) return;
  float t0[K_B], t1[K_B];
#pragma unroll
  for (int k = 0; k < K_B; ++k) { t0[k] = T[i * 8 + k]; t1[k] = T[(size_t)I_F * 8 + i * 8 + k]; }
  const float4 wa = ((const float4*)W)[i * 2];
  const float4 wb = ((const float4*)W)[i * 2 + 1];
  float num0[K_B] = {}, den0[K_B] = {}, num1[K_B] = {}, den1[K_B] = {};
  const int jend = min(PJSZ, J_F - j0);
#pragma unroll 4
  for (int jj = 0; jj < jend; ++jj) {
    const int j = j0 + jj;
    float2 x0 = X[(size_t)j * I_F + i];
    float2 x1 = X[(size_t)(J_F + j) * I_F + i];
    float yr = wa.x * x0.x - wa.y * x0.y + wa.z * x1.x - wa.w * x1.y;
    float yi = wa.x * x0.y + wa.y * x0.x + wa.z * x1.y + wa.w * x1.x;
    float p0 = yr * yr + yi * yi;
    float zr = wb.x * x0.x - wb.y * x0.y + wb.z * x1.x - wb.w * x1.y;
    float zi = wb.x * x0.y + wb.y * x0.x + wb.z * x1.y + wb.w * x1.x;
    float p1 = zr * zr + zi * zi;
    P[(size_t)j * I_F + i] = p0;
    P[(size_t)(J_F + j) * I_F + i] = p1;
    float R0 = 0.f, R1 = 0.f;
    float v0[K_B], v1[K_B];
#pragma unroll
    for (int k = 0; k < K_B; ++k) {
      v0[k] = Vl[0][k][jj]; R0 += t0[k] * v0[k];
      v1[k] = Vl[1][k][jj]; R1 += t1[k] * v1[k];
    }
    float a0 = p0 / (R0 * R0), b0 = 1.f / R0;
    float a1 = p1 / (R1 * R1), b1 = 1.f / R1;
#pragma unroll
    for (int k = 0; k < K_B; ++k) {
      num0[k] += a0 * v0[k]; den0[k] += b0 * v0[k];
      num1[k] += a1 * v1[k]; den1[k] += b1 * v1[k];
    }
  }
  // Tpart[n][jt][i][16], float4 stores (lane-local, no reduction needed)
  float* base0 = Tpart + (((size_t)0 * PJT + blockIdx.y) * IB + i) * 16;
  float* base1 = Tpart + (((size_t)1 * PJT + blockIdx.y) * IB + i) * 16;
  *(float4*)(base0 + 0)  = make_float4(num0[0], num0[1], num0[2], num0[3]);
  *(float4*)(base0 + 4)  = make_float4(num0[4], num0[5], num0[6], num0[7]);
  *(float4*)(base0 + 8)  = make_float4(den0[0], den0[1], den0[2], den0[3]);
  *(float4*)(base0 + 12) = make_float4(den0[4], den0[5], den0[6], den0[7]);
  *(float4*)(base1 + 0)  = make_float4(num1[0], num1[1], num1[2], num1[3]);
  *(float4*)(base1 + 4)  = make_float4(num1[4], num1[5], num1[6], num1[7]);
  *(float4*)(base1 + 8)  = make_float4(den1[0], den1[1], den1[2], den1[3]);
  *(float4*)(base1 + 12) = make_float4(den1[4], den1[5], den1[6], den1[7]);
}

// ---------------- finish T update from partials ----------------
__global__ __launch_bounds__(256) void k_t_finish(const float* __restrict__ Tpart,
                                                  float* __restrict__ T) {
  int t = blockIdx.x * 256 + threadIdx.x;
  if (t >= 2 * I_F * K_B) return;
  int n = t / (I_F * K_B);
  int r = t % (I_F * K_B);
  int i = r >> 3, k = r & 7;
  float num = 0.f, den = 0.f;
  for (int jt = 0; jt < PJT; ++jt) {
    const float* p = Tpart + (((size_t)n * PJT + jt) * IB + i) * 16;
    num += p[k]; den += p[8 + k];
  }
  float told = T[t];
  T[t] = fmaxf(told * sqrtf(num / den), NMF_EPS);
}

// ------- V update: one block per (j,n), full reduction over i, in place -------
__global__ __launch_bounds__(256) void k_v_update(const float* __restrict__ P,
                                                  const float* __restrict__ T,
                                                  float* __restrict__ V) {
  const int j = blockIdx.x;
  const int n = blockIdx.y;
  const int tid = threadIdx.x;
  const float* Pn = P + ((size_t)n * J_F + j) * I_F;
  const float* Tn = T + (size_t)n * I_F * K_B;
  float vold[K_B];
#pragma unroll
  for (int k = 0; k < K_B; ++k) vold[k] = V[((size_t)n * K_B + k) * J_F + j];
  float num[K_B] = {}, den[K_B] = {};
  for (int i = tid; i < I_F; i += 256) {
    float p = Pn[i];
    const float4 ta = *(const float4*)&Tn[i * 8];
    const float4 tb = *(const float4*)&Tn[i * 8 + 4];
    float tk[K_B] = {ta.x, ta.y, ta.z, ta.w, tb.x, tb.y, tb.z, tb.w};
    float R = 0.f;
#pragma unroll
    for (int k = 0; k < K_B; ++k) R += tk[k] * vold[k];
    float a = p / (R * R);
    float b = 1.0f / R;
#pragma unroll
    for (int k = 0; k < K_B; ++k) { num[k] += a * tk[k]; den[k] += b * tk[k]; }
  }
  __shared__ float red[4][16];
  const int lane = tid & 63, wid = tid >> 6;
#pragma unroll
  for (int k = 0; k < K_B; ++k) {
    float a = num[k], b = den[k];
#pragma unroll
    for (int off = 32; off > 0; off >>= 1) {
      a += __shfl_xor(a, off, 64);
      b += __shfl_xor(b, off, 64);
    }
    if (lane == 0) { red[wid][k] = a; red[wid][8 + k] = b; }
  }
  __syncthreads();
  if (tid < 16) red[0][tid] = red[0][tid] + red[1][tid] + red[2][tid] + red[3][tid];
  __syncthreads();
  if (tid < 8) {
    float vo = V[((size_t)n * K_B + tid) * J_F + j];
    V[((size_t)n * K_B + tid) * J_F + j] =
        fmaxf(vo * sqrtf(red[0][tid] / red[0][8 + tid]), NMF_EPS);
  }
}

// -------- weighted covariance partials, both n share X loads --------
__global__ __launch_bounds__(256) void k_d_partial(const float2* __restrict__ X,
                                                   const float* __restrict__ T,
                                                   const float* __restrict__ V,
                                                   float* __restrict__ Dpart) {
  __shared__ float Vl[2][K_B][JCHSZ];
  const int tid = threadIdx.x;
  const int j0 = blockIdx.y * JCHSZ;
  for (int idx = tid; idx < 2 * K_B * JCHSZ; idx += 256) {
    int n = idx / (K_B * JCHSZ), r = idx % (K_B * JCHSZ);
    int k = r / JCHSZ, jj = r % JCHSZ;
    Vl[n][k][jj] = V[((size_t)n * K_B + k) * J_F + j0 + jj];
  }
  __syncthreads();
  const int i = blockIdx.x * 256 + tid;
  if (i >= I_F) return;
  float t0[K_B], t1[K_B];
#pragma unroll
  for (int k = 0; k < K_B; ++k) { t0[k] = T[i * K_B + k]; t1[k] = T[(size_t)I_F * K_B + i * K_B + k]; }
  float a00 = 0.f, a11 = 0.f, a01r = 0.f, a01i = 0.f;
  float b00 = 0.f, b11 = 0.f, b01r = 0.f, b01i = 0.f;
  for (int jj = 0; jj < JCHSZ; ++jj) {
    int j = j0 + jj;
    float R0 = 0.f, R1 = 0.f;
#pragma unroll
    for (int k = 0; k < K_B; ++k) {
      R0 += t0[k] * Vl[0][k][jj];
      R1 += t1[k] * Vl[1][k][jj];
    }
    float wv0 = 1.0f / (R0 + IP_EPS);
    float wv1 = 1.0f / (R1 + IP_EPS);
    float2 x0 = X[(size_t)j * I_F + i];
    float2 x1 = X[(size_t)(J_F + j) * I_F + i];
    float p00 = x0.x * x0.x + x0.y * x0.y;
    float p11 = x1.x * x1.x + x1.y * x1.y;
    float pr = x0.x * x1.x + x0.y * x1.y;
    float pi = x0.y * x1.x - x0.x * x1.y;
    a00 += wv0 * p00; a11 += wv0 * p11; a01r += wv0 * pr; a01i += wv0 * pi;
    b00 += wv1 * p00; b11 += wv1 * p11; b01r += wv1 * pr; b01i += wv1 * pi;
  }
  float4* dp = (float4*)Dpart;
  dp[((size_t)0 * JCH + blockIdx.y) * I_F + i] = make_float4(a00, a11, a01r, a01i);
  dp[((size_t)1 * JCH + blockIdx.y) * I_F + i] = make_float4(b00, b11, b01r, b01i);
}

// -------- combine D + sequential 2x2 complex solves (n=0 then n=1) --------
__global__ __launch_bounds__(256) void k_d_solve(const float* __restrict__ Dpart,
                                                 float* __restrict__ W) {
  const int i = blockIdx.x * 256 + threadIdx.x;
  if (i >= I_F) return;
  float4 wa = ((const float4*)W)[i * 2];
  float4 wb = ((const float4*)W)[i * 2 + 1];
  float w00r = wa.x, w00i = wa.y, w01r = wa.z, w01i = wa.w;
  float w10r = wb.x, w10i = wb.y, w11r = wb.z, w11i = wb.w;
  const float invJ = 1.0f / (float)J_F;
#pragma unroll
  for (int n = 0; n < 2; ++n) {
    float d00 = 0.f, d11 = 0.f, d01r = 0.f, d01i = 0.f;
    for (int c = 0; c < JCH; ++c) {
      float4 d = ((const float4*)Dpart)[((size_t)n * JCH + c) * I_F + i];
      d00 += d.x; d11 += d.y; d01r += d.z; d01i += d.w;
    }
    d00 = d00 * invJ + IP_EPS;
    d11 = d11 * invJ + IP_EPS;
    d01r *= invJ; d01i *= invJ;
    float A00r = w00r * d00 + (w01r * d01r + w01i * d01i);
    float A00i = w00i * d00 + (w01i * d01r - w01r * d01i);
    float A01r = (w00r * d01r - w00i * d01i) + w01r * d11;
    float A01i = (w00r * d01i + w00i * d01r) + w01i * d11;
    float A10r = w10r * d00 + (w11r * d01r + w11i * d01i);
    float A10i = w10i * d00 + (w11i * d01r - w11r * d01i);
    float A11r = (w10r * d01r - w10i * d01i) + w11r * d11;
    float A11i = (w10r * d01i + w10i * d01r) + w11i * d11;
    float detr = (A00r * A11r - A00i * A11i) - (A01r * A10r - A01i * A10i);
    float deti = (A00r * A11i + A00i * A11r) - (A01r * A10i + A01i * A10r);
    float idet = 1.0f / (detr * detr + deti * deti);
    float n0r, n0i, n1r, n1i;
    if (n == 0) { n0r = A11r; n0i = A11i; n1r = -A10r; n1i = -A10i; }
    else        { n0r = -A01r; n0i = -A01i; n1r = A00r; n1i = A00i; }
    float b0r = (n0r * detr + n0i * deti) * idet;
    float b0i = (n0i * detr - n0r * deti) * idet;
    float b1r = (n1r * detr + n1i * deti) * idet;
    float b1i = (n1i * detr - n1r * deti) * idet;
    float cr = d01r * b1r - d01i * b1i;
    float ci = d01r * b1i + d01i * b1r;
    float quad = d00 * (b0r * b0r + b0i * b0i) + d11 * (b1r * b1r + b1i * b1i)
               + 2.0f * (b0r * cr + b0i * ci);
    float s = 1.0f / sqrtf(quad + IP_EPS);
    if (n == 0) { w00r = b0r * s; w00i = -b0i * s; w01r = b1r * s; w01i = -b1i * s; }
    else        { w10r = b0r * s; w10i = -b0i * s; w11r = b1r * s; w11i = -b1i * s; }
  }
  ((float4*)W)[i * 2]     = make_float4(w00r, w00i, w01r, w01i);
  ((float4*)W)[i * 2 + 1] = make_float4(w10r, w10i, w11r, w11i);
}

// ---------------- final: out[n][j][i][2] = Y[i,n,j] ----------------
__global__ __launch_bounds__(256) void k_final(const float2* __restrict__ X,
                                               const float* __restrict__ W,
                                               float2* __restrict__ out) {
  const int i = blockIdx.x * 256 + threadIdx.x;
  if (i >= I_F) return;
  const float4 wa = ((const float4*)W)[i * 2];
  const float4 wb = ((const float4*)W)[i * 2 + 1];
  const int j0 = blockIdx.y * 16;
  const int jend = min(16, J_F - j0);
  for (int jj = 0; jj < jend; ++jj) {
    const int j = j0 + jj;
    float2 x0 = X[(size_t)j * I_F + i];
    float2 x1 = X[(size_t)(J_F + j) * I_F + i];
    float y0r = wa.x * x0.x - wa.y * x0.y + wa.z * x1.x - wa.w * x1.y;
    float y0i = wa.x * x0.y + wa.y * x0.x + wa.z * x1.y + wa.w * x1.x;
    out[(size_t)j * I_F + i] = make_float2(y0r, y0i);
    float y1r = wb.x * x0.x - wb.y * x0.y + wb.z * x1.x - wb.w * x1.y;
    float y1i = wb.x * x0.y + wb.y * x0.x + wb.z * x1.y + wb.w * x1.x;
    out[(size_t)(J_F + j) * I_F + i] = make_float2(y1r, y1i);
  }
}

extern "C" void kernel_launch(void* const* d_in, const int* in_sizes, int n_in,
                              void* d_out, int out_size, void* d_ws, size_t ws_size,
                              hipStream_t stream) {
  const float2* X = (const float2*)d_in[0];
  const float* T0 = (const float*)d_in[1];
  const float* V0 = (const float*)d_in[2];
  char* ws = (char*)d_ws;
  size_t off = 0;
  auto alloc = [&](size_t bytes) -> void* {
    void* p = ws + off;
    off = (off + bytes + 255) & ~(size_t)255;
    return p;
  };
  float* W = (float*)alloc((size_t)I_F * 8 * 4);
  float* T = (float*)alloc((size_t)2 * I_F * K_B * 4);
  float* V = (float*)alloc((size_t)2 * K_B * J_F * 4);
  float* P = (float*)alloc((size_t)2 * I_F * J_F * 4);
  // Tpart (18.9 MB) and Dpart (3.3 MB) have disjoint lifetimes -> share
  float* Scr = (float*)alloc((size_t)2 * PJT * IB * 16 * 4);
  float* Tpart = Scr;
  float* Dpart = Scr;

  k_init<<<128, 256, 0, stream>>>(T0, V0, T, V, W);
  for (int it = 0; it < N_IT; ++it) {
    k_P_T<<<dim3(9, PJT), 256, 0, stream>>>(X, W, T, V, P, Tpart);
    k_t_finish<<<129, 256, 0, stream>>>(Tpart, T);
    k_v_update<<<dim3(J_F, 2), 256, 0, stream>>>(P, T, V);
    k_d_partial<<<dim3(9, JCH), 256, 0, stream>>>(X, T, V, Dpart);
    k_d_solve<<<9, 256, 0, stream>>>(Dpart, W);
  }
  k_final<<<dim3(9, 125), 256, 0, stream>>>(X, W, (float2*)d_out);
}